// Round 6
// baseline (176.133 us; speedup 1.0000x reference)
//
#include <hip/hip_runtime.h>
#include <math.h>

#define NB 32
#define NS 4096
#define ND 160
#define ND4 40              // ND in float4
#define NM 16
#define NR 16
#define TPB 64              // tokens per block
#define NCB (NS / TPB)      // 64 chunks per batch

typedef float f32x4 __attribute__((ext_vector_type(4)));

// ---------------------------------------------------------------------------
// Kernel 0: fold weights per batch:
//   K[m][d] = 0.25 * sum_r mem16[m][r] * Wrk[r][d]
//   V[m][d] =        sum_r mem16[m][r] * Wrv[d][r]
// kvbuf layout: [NB][2][NM][ND]  (K plane then V plane)
// grid = NB, block = 256
// ---------------------------------------------------------------------------
__global__ __launch_bounds__(256) void ulm_fold_kv(
    const float* __restrict__ memory,
    const float* __restrict__ Wrk,     // [NR][ND]
    const float* __restrict__ Wrv,     // [ND][NR]
    float* __restrict__ kvbuf)
{
    __shared__ float sM16[NM * NR];
    const int b = blockIdx.x;
    const int t = threadIdx.x;
    {
        int m = t >> 4, r = t & 15;
        sM16[t] = memory[((size_t)b * NM + m) * ND + r];
    }
    __syncthreads();
    if (t < ND) {
        float wk[NR], wv[NR];
#pragma unroll
        for (int r = 0; r < NR; ++r) wk[r] = Wrk[r * ND + t];
        const float4* wrv4 = reinterpret_cast<const float4*>(Wrv + t * NR);
#pragma unroll
        for (int j = 0; j < 4; ++j) {
            float4 v = wrv4[j];
            wv[j * 4 + 0] = v.x; wv[j * 4 + 1] = v.y;
            wv[j * 4 + 2] = v.z; wv[j * 4 + 3] = v.w;
        }
        float* kb = kvbuf + (size_t)b * 2 * NM * ND;
#pragma unroll
        for (int m = 0; m < NM; ++m) {
            float aK = 0.f, aV = 0.f;
#pragma unroll
            for (int r = 0; r < NR; ++r) {
                float mv = sM16[m * NR + r];
                aK += mv * wk[r];
                aV += mv * wv[r];
            }
            kb[m * ND + t]           = aK * 0.25f;   // fold 1/sqrt(R)
            kb[NM * ND + m * ND + t] = aV;
        }
    }
}

// ---------------------------------------------------------------------------
// Kernel 1: read path. scores = q·K^T, softmax, out = attn·V.
// K/V read straight from global kvbuf (L1/L2-hot: 20 KB/batch, all lanes of a
// wave hit the same 128 B line per (m,k) -> broadcast). No K/V LDS, no staging
// barrier: LDS = 2.5 KB -> residency capped only by grid (8 blocks/CU).
// Fused: partial column-sums of `interface` -> ipart.
// grid = (NCB, NB), block = 256. 8 lanes per group, 2 tokens per group.
// ---------------------------------------------------------------------------
__global__ __launch_bounds__(256, 6) void ulm_read_kernel(
    const float* __restrict__ query,
    const float* __restrict__ iface,
    const float* __restrict__ kvbuf,   // [NB][2][NM][ND]
    float* __restrict__ read_out,      // [NB][NS][ND]
    float* __restrict__ ipart)         // [NB][NCB][ND]
{
    __shared__ float4 sIred[4 * ND4];                 // 2.5 KB only

    const int t = threadIdx.x;
    const int chunk = blockIdx.x;
    const int b = blockIdx.y;
    const int s0 = chunk * TPB;

    const float4* kK4 = reinterpret_cast<const float4*>(kvbuf + (size_t)b * 2 * NM * ND);
    const float4* kV4 = kK4 + NM * ND4;

    const int l = t & 7;                  // lane in 8-lane group
    const int G = t >> 3;                 // group 0..31
    const int tok0 = G * 2, tok1 = tok0 + 1;

    const float4* q4 = reinterpret_cast<const float4*>(query + ((size_t)b * NS + s0) * ND);

    // --- scores: 16 dots of length 160, 8-lane distributed ------------------
    float sc0[NM], sc1[NM];
#pragma unroll
    for (int m = 0; m < NM; ++m) { sc0[m] = 0.f; sc1[m] = 0.f; }

#pragma unroll
    for (int k = 0; k < 5; ++k) {
        float4 qa = q4[tok0 * ND4 + l + 8 * k];
        float4 qb = q4[tok1 * ND4 + l + 8 * k];
#pragma unroll
        for (int m = 0; m < NM; ++m) {
            float4 kv = kK4[m * ND4 + l + 8 * k];
            sc0[m] += qa.x * kv.x + qa.y * kv.y + qa.z * kv.z + qa.w * kv.w;
            sc1[m] += qb.x * kv.x + qb.y * kv.y + qb.z * kv.z + qb.w * kv.w;
        }
    }
#pragma unroll
    for (int m = 0; m < NM; ++m) {
        sc0[m] += __shfl_xor(sc0[m], 1);
        sc0[m] += __shfl_xor(sc0[m], 2);
        sc0[m] += __shfl_xor(sc0[m], 4);
        sc1[m] += __shfl_xor(sc1[m], 1);
        sc1[m] += __shfl_xor(sc1[m], 2);
        sc1[m] += __shfl_xor(sc1[m], 4);
    }

    // --- softmax (redundant per lane; 16-wide) -----------------------------
    float mx0 = -1e30f, mx1 = -1e30f;
#pragma unroll
    for (int m = 0; m < NM; ++m) { mx0 = fmaxf(mx0, sc0[m]); mx1 = fmaxf(mx1, sc1[m]); }
    float sm0 = 0.f, sm1 = 0.f;
#pragma unroll
    for (int m = 0; m < NM; ++m) {
        sc0[m] = __expf(sc0[m] - mx0); sm0 += sc0[m];
        sc1[m] = __expf(sc1[m] - mx1); sm1 += sc1[m];
    }
    float inv0 = 1.f / sm0, inv1 = 1.f / sm1;
#pragma unroll
    for (int m = 0; m < NM; ++m) { sc0[m] *= inv0; sc1[m] *= inv1; }

    // --- iface partial sums: load + immediate butterfly per k --------------
    const float4* i4 = reinterpret_cast<const float4*>(iface + ((size_t)b * NS + s0) * ND);
    const int w = t >> 6;
#pragma unroll
    for (int k = 0; k < 5; ++k) {
        float4 va = i4[tok0 * ND4 + l + 8 * k];
        float4 vb = i4[tok1 * ND4 + l + 8 * k];
        float x = va.x + vb.x, y = va.y + vb.y;
        float z = va.z + vb.z, u = va.w + vb.w;
#pragma unroll
        for (int off = 8; off <= 32; off <<= 1) {
            x += __shfl_xor(x, off); y += __shfl_xor(y, off);
            z += __shfl_xor(z, off); u += __shfl_xor(u, off);
        }
        if ((t & 63) < 8) sIred[w * ND4 + k * 8 + l] = make_float4(x, y, z, u);
    }

    // --- out = attn · V (nontemporal: output never re-read) -----------------
    float4* out4 = reinterpret_cast<float4*>(read_out + ((size_t)b * NS + s0) * ND);
#pragma unroll
    for (int k = 0; k < 5; ++k) {
        float4 o0 = make_float4(0.f, 0.f, 0.f, 0.f);
        float4 o1 = make_float4(0.f, 0.f, 0.f, 0.f);
#pragma unroll
        for (int m = 0; m < NM; ++m) {
            float4 vv = kV4[m * ND4 + l + 8 * k];
            o0.x += sc0[m] * vv.x; o0.y += sc0[m] * vv.y;
            o0.z += sc0[m] * vv.z; o0.w += sc0[m] * vv.w;
            o1.x += sc1[m] * vv.x; o1.y += sc1[m] * vv.y;
            o1.z += sc1[m] * vv.z; o1.w += sc1[m] * vv.w;
        }
        f32x4 ov0; ov0.x = o0.x; ov0.y = o0.y; ov0.z = o0.z; ov0.w = o0.w;
        f32x4 ov1; ov1.x = o1.x; ov1.y = o1.y; ov1.z = o1.z; ov1.w = o1.w;
        __builtin_nontemporal_store(ov0,
            reinterpret_cast<f32x4*>(out4 + tok0 * ND4 + l + 8 * k));
        __builtin_nontemporal_store(ov1,
            reinterpret_cast<f32x4*>(out4 + tok1 * ND4 + l + 8 * k));
    }

    // --- finish interface reduction: 4 wave-partials -> 1, store to ws -----
    __syncthreads();
    if (t < ND4) {
        float4 a0 = sIred[t], a1 = sIred[ND4 + t];
        float4 a2 = sIred[2 * ND4 + t], a3 = sIred[3 * ND4 + t];
        float4 tot = make_float4(a0.x + a1.x + a2.x + a3.x,
                                 a0.y + a1.y + a2.y + a3.y,
                                 a0.z + a1.z + a2.z + a3.z,
                                 a0.w + a1.w + a2.w + a3.w);
        reinterpret_cast<float4*>(ipart + ((size_t)(b * NCB + chunk)) * ND)[t] = tot;
    }
}

// ---------------------------------------------------------------------------
// Kernel 2: write path. i_mean -> i_proj -> erase/add -> layer_norm(new_mem)
// grid = NB, block = 256
// ---------------------------------------------------------------------------
__global__ __launch_bounds__(256) void ulm_write_kernel(
    const float* __restrict__ memory,
    const float* __restrict__ Wwk,     // [NR][ND]
    const float* __restrict__ Wwe,     // [ND][NR]
    const float* __restrict__ Wwa,     // [ND][NR]
    const float* __restrict__ ipart,   // [NB][NCB][ND]
    float* __restrict__ new_mem)       // [NB][NM][ND]
{
    __shared__ float sIm[ND];
    __shared__ float sIp[NR];
    __shared__ float sOmE[ND];   // 1 - erase
    __shared__ float sAdd[ND];

    const int b = blockIdx.x;
    const int t = threadIdx.x;

    if (t < ND) {
        float acc = 0.f;
#pragma unroll 8
        for (int c = 0; c < NCB; ++c)
            acc += ipart[((size_t)(b * NCB + c)) * ND + t];
        sIm[t] = acc * (1.0f / NS);
    }
    __syncthreads();

    if (t < NR) {
        float acc = 0.f;
        for (int d = 0; d < ND; ++d) acc += sIm[d] * Wwk[t * ND + d];
        sIp[t] = acc;
    }
    __syncthreads();

    if (t < ND) {
        float e = 0.f, a = 0.f;
#pragma unroll
        for (int r = 0; r < NR; ++r) {
            float ip = sIp[r];
            e += ip * Wwe[t * NR + r];
            a += ip * Wwa[t * NR + r];
        }
        sOmE[t] = 1.0f - 1.0f / (1.0f + __expf(-e));
        sAdd[t] = a;
    }
    __syncthreads();

    // layer norm each of the 16 memory rows; one wave per row
    const int wave = t >> 6, lane = t & 63;
    for (int m = wave; m < NM; m += 4) {
        const float* mrow = memory + ((size_t)b * NM + m) * ND;
        float v0 = mrow[lane] * sOmE[lane] + sAdd[lane];
        float v1 = mrow[lane + 64] * sOmE[lane + 64] + sAdd[lane + 64];
        float v2 = 0.f;
        const bool has2 = lane < 32;
        if (has2) v2 = mrow[lane + 128] * sOmE[lane + 128] + sAdd[lane + 128];
        float s  = v0 + v1 + v2;
        float sq = v0 * v0 + v1 * v1 + v2 * v2;
#pragma unroll
        for (int off = 32; off; off >>= 1) {
            s  += __shfl_xor(s, off);
            sq += __shfl_xor(sq, off);
        }
        float mu   = s * (1.0f / ND);
        float var  = sq * (1.0f / ND) - mu * mu;
        float rstd = rsqrtf(var + 1e-5f);
        float* orow = new_mem + ((size_t)b * NM + m) * ND;
        orow[lane]      = (v0 - mu) * rstd;
        orow[lane + 64] = (v1 - mu) * rstd;
        if (has2) orow[lane + 128] = (v2 - mu) * rstd;
    }
}

extern "C" void kernel_launch(void* const* d_in, const int* in_sizes, int n_in,
                              void* d_out, int out_size, void* d_ws, size_t ws_size,
                              hipStream_t stream) {
    const float* query  = (const float*)d_in[0];
    const float* iface  = (const float*)d_in[1];
    const float* memory = (const float*)d_in[2];
    const float* Wrk    = (const float*)d_in[3];
    const float* Wrv    = (const float*)d_in[4];
    const float* Wwk    = (const float*)d_in[5];
    const float* Wwe    = (const float*)d_in[6];
    const float* Wwa    = (const float*)d_in[7];

    float* read_out = (float*)d_out;                        // [32][4096][160]
    float* new_mem  = (float*)d_out + (size_t)NB * NS * ND; // [32][16][160]
    float* ipart    = (float*)d_ws;                         // NB*NCB*ND f32
    float* kvbuf    = (float*)d_ws + (size_t)NB * NCB * ND; // NB*2*NM*ND f32

    ulm_fold_kv<<<NB, 256, 0, stream>>>(memory, Wrk, Wrv, kvbuf);
    dim3 grid1(NCB, NB);
    ulm_read_kernel<<<grid1, 256, 0, stream>>>(query, iface, kvbuf,
                                               read_out, ipart);
    ulm_write_kernel<<<NB, 256, 0, stream>>>(memory, Wwk, Wwe, Wwa, ipart, new_mem);
}

// Round 7
// 70.738 us; speedup vs baseline: 2.4899x; 2.4899x over previous
//
#include <hip/hip_runtime.h>
#include <math.h>

#define NB 32
#define NS 4096
#define ND 160
#define ND4 40              // ND in float4
#define NM 16
#define NR 16
#define TPB 64              // tokens per block
#define NCB (NS / TPB)      // 64 chunks per batch

typedef float f32x4 __attribute__((ext_vector_type(4)));

// ---------------------------------------------------------------------------
// Kernel 0: fold weights per batch:
//   K[m][d] = 0.25 * sum_r mem16[m][r] * Wrk[r][d]
//   V[m][d] =        sum_r mem16[m][r] * Wrv[d][r]
// kvbuf layout: [NB][2][NM][ND]  (K plane then V plane)
// grid = NB, block = 256
// ---------------------------------------------------------------------------
__global__ __launch_bounds__(256) void ulm_fold_kv(
    const float* __restrict__ memory,
    const float* __restrict__ Wrk,     // [NR][ND]
    const float* __restrict__ Wrv,     // [ND][NR]
    float* __restrict__ kvbuf)
{
    __shared__ float sM16[NM * NR];
    const int b = blockIdx.x;
    const int t = threadIdx.x;
    {
        int m = t >> 4, r = t & 15;
        sM16[t] = memory[((size_t)b * NM + m) * ND + r];
    }
    __syncthreads();
    if (t < ND) {
        float wk[NR], wv[NR];
#pragma unroll
        for (int r = 0; r < NR; ++r) wk[r] = Wrk[r * ND + t];
        const float4* wrv4 = reinterpret_cast<const float4*>(Wrv + t * NR);
#pragma unroll
        for (int j = 0; j < 4; ++j) {
            float4 v = wrv4[j];
            wv[j * 4 + 0] = v.x; wv[j * 4 + 1] = v.y;
            wv[j * 4 + 2] = v.z; wv[j * 4 + 3] = v.w;
        }
        float* kb = kvbuf + (size_t)b * 2 * NM * ND;
#pragma unroll
        for (int m = 0; m < NM; ++m) {
            float aK = 0.f, aV = 0.f;
#pragma unroll
            for (int r = 0; r < NR; ++r) {
                float mv = sM16[m * NR + r];
                aK += mv * wk[r];
                aV += mv * wv[r];
            }
            kb[m * ND + t]           = aK * 0.25f;   // fold 1/sqrt(R)
            kb[NM * ND + m * ND + t] = aV;
        }
    }
}

// ---------------------------------------------------------------------------
// Kernel 1: read path. scores = q·K^T, softmax, out = attn·V.
// K/V read directly from global kvbuf (20 KB/batch, L1/L2-hot; each load
// instruction touches one 128 B line shared by all 8 groups of the wave).
// LDS = 2.5 KB only; no staging barrier. NO VGPR cap: natural footprint is
// ~50-64 regs (sc0[16]+sc1[16]+addressing). R4/R6 proved caps => spills =>
// 2-5x HBM amplification. Grid 2048 blocks = 8 blocks/CU -> 32 waves/CU.
// Fused: partial column-sums of `interface` -> ipart.
// grid = (NCB, NB), block = 256. 8 lanes per group, 2 tokens per group.
// ---------------------------------------------------------------------------
__global__ __launch_bounds__(256) void ulm_read_kernel(
    const float* __restrict__ query,
    const float* __restrict__ iface,
    const float* __restrict__ kvbuf,   // [NB][2][NM][ND]
    float* __restrict__ read_out,      // [NB][NS][ND]
    float* __restrict__ ipart)         // [NB][NCB][ND]
{
    __shared__ float4 sIred[4 * ND4];                 // 2.5 KB only

    const int t = threadIdx.x;
    const int chunk = blockIdx.x;
    const int b = blockIdx.y;
    const int s0 = chunk * TPB;

    const float4* kK4 = reinterpret_cast<const float4*>(kvbuf + (size_t)b * 2 * NM * ND);
    const float4* kV4 = kK4 + NM * ND4;

    const int l = t & 7;                  // lane in 8-lane group
    const int G = t >> 3;                 // group 0..31
    const int tok0 = G * 2, tok1 = tok0 + 1;

    const float4* q4 = reinterpret_cast<const float4*>(query + ((size_t)b * NS + s0) * ND);

    // --- scores: 16 dots of length 160, 8-lane distributed ------------------
    float sc0[NM], sc1[NM];
#pragma unroll
    for (int m = 0; m < NM; ++m) { sc0[m] = 0.f; sc1[m] = 0.f; }

#pragma unroll
    for (int k = 0; k < 5; ++k) {
        float4 qa = q4[tok0 * ND4 + l + 8 * k];
        float4 qb = q4[tok1 * ND4 + l + 8 * k];
#pragma unroll
        for (int m = 0; m < NM; ++m) {
            float4 kv = kK4[m * ND4 + l + 8 * k];
            sc0[m] += qa.x * kv.x + qa.y * kv.y + qa.z * kv.z + qa.w * kv.w;
            sc1[m] += qb.x * kv.x + qb.y * kv.y + qb.z * kv.z + qb.w * kv.w;
        }
    }
#pragma unroll
    for (int m = 0; m < NM; ++m) {
        sc0[m] += __shfl_xor(sc0[m], 1);
        sc0[m] += __shfl_xor(sc0[m], 2);
        sc0[m] += __shfl_xor(sc0[m], 4);
        sc1[m] += __shfl_xor(sc1[m], 1);
        sc1[m] += __shfl_xor(sc1[m], 2);
        sc1[m] += __shfl_xor(sc1[m], 4);
    }

    // --- softmax (redundant per lane; 16-wide) -----------------------------
    float mx0 = -1e30f, mx1 = -1e30f;
#pragma unroll
    for (int m = 0; m < NM; ++m) { mx0 = fmaxf(mx0, sc0[m]); mx1 = fmaxf(mx1, sc1[m]); }
    float sm0 = 0.f, sm1 = 0.f;
#pragma unroll
    for (int m = 0; m < NM; ++m) {
        sc0[m] = __expf(sc0[m] - mx0); sm0 += sc0[m];
        sc1[m] = __expf(sc1[m] - mx1); sm1 += sc1[m];
    }
    float inv0 = 1.f / sm0, inv1 = 1.f / sm1;
#pragma unroll
    for (int m = 0; m < NM; ++m) { sc0[m] *= inv0; sc1[m] *= inv1; }

    // --- iface partial sums: load + immediate butterfly per k --------------
    const float4* i4 = reinterpret_cast<const float4*>(iface + ((size_t)b * NS + s0) * ND);
    const int w = t >> 6;
#pragma unroll
    for (int k = 0; k < 5; ++k) {
        float4 va = i4[tok0 * ND4 + l + 8 * k];
        float4 vb = i4[tok1 * ND4 + l + 8 * k];
        float x = va.x + vb.x, y = va.y + vb.y;
        float z = va.z + vb.z, u = va.w + vb.w;
#pragma unroll
        for (int off = 8; off <= 32; off <<= 1) {
            x += __shfl_xor(x, off); y += __shfl_xor(y, off);
            z += __shfl_xor(z, off); u += __shfl_xor(u, off);
        }
        if ((t & 63) < 8) sIred[w * ND4 + k * 8 + l] = make_float4(x, y, z, u);
    }

    // --- out = attn · V (nontemporal: output never re-read) -----------------
    float4* out4 = reinterpret_cast<float4*>(read_out + ((size_t)b * NS + s0) * ND);
#pragma unroll
    for (int k = 0; k < 5; ++k) {
        float4 o0 = make_float4(0.f, 0.f, 0.f, 0.f);
        float4 o1 = make_float4(0.f, 0.f, 0.f, 0.f);
#pragma unroll
        for (int m = 0; m < NM; ++m) {
            float4 vv = kV4[m * ND4 + l + 8 * k];
            o0.x += sc0[m] * vv.x; o0.y += sc0[m] * vv.y;
            o0.z += sc0[m] * vv.z; o0.w += sc0[m] * vv.w;
            o1.x += sc1[m] * vv.x; o1.y += sc1[m] * vv.y;
            o1.z += sc1[m] * vv.z; o1.w += sc1[m] * vv.w;
        }
        f32x4 ov0; ov0.x = o0.x; ov0.y = o0.y; ov0.z = o0.z; ov0.w = o0.w;
        f32x4 ov1; ov1.x = o1.x; ov1.y = o1.y; ov1.z = o1.z; ov1.w = o1.w;
        __builtin_nontemporal_store(ov0,
            reinterpret_cast<f32x4*>(out4 + tok0 * ND4 + l + 8 * k));
        __builtin_nontemporal_store(ov1,
            reinterpret_cast<f32x4*>(out4 + tok1 * ND4 + l + 8 * k));
    }

    // --- finish interface reduction: 4 wave-partials -> 1, store to ws -----
    __syncthreads();
    if (t < ND4) {
        float4 a0 = sIred[t], a1 = sIred[ND4 + t];
        float4 a2 = sIred[2 * ND4 + t], a3 = sIred[3 * ND4 + t];
        float4 tot = make_float4(a0.x + a1.x + a2.x + a3.x,
                                 a0.y + a1.y + a2.y + a3.y,
                                 a0.z + a1.z + a2.z + a3.z,
                                 a0.w + a1.w + a2.w + a3.w);
        reinterpret_cast<float4*>(ipart + ((size_t)(b * NCB + chunk)) * ND)[t] = tot;
    }
}

// ---------------------------------------------------------------------------
// Kernel 2: write path. i_mean -> i_proj -> erase/add -> layer_norm(new_mem)
// grid = NB, block = 256
// ---------------------------------------------------------------------------
__global__ __launch_bounds__(256) void ulm_write_kernel(
    const float* __restrict__ memory,
    const float* __restrict__ Wwk,     // [NR][ND]
    const float* __restrict__ Wwe,     // [ND][NR]
    const float* __restrict__ Wwa,     // [ND][NR]
    const float* __restrict__ ipart,   // [NB][NCB][ND]
    float* __restrict__ new_mem)       // [NB][NM][ND]
{
    __shared__ float sIm[ND];
    __shared__ float sIp[NR];
    __shared__ float sOmE[ND];   // 1 - erase
    __shared__ float sAdd[ND];

    const int b = blockIdx.x;
    const int t = threadIdx.x;

    if (t < ND) {
        float acc = 0.f;
#pragma unroll 8
        for (int c = 0; c < NCB; ++c)
            acc += ipart[((size_t)(b * NCB + c)) * ND + t];
        sIm[t] = acc * (1.0f / NS);
    }
    __syncthreads();

    if (t < NR) {
        float acc = 0.f;
        for (int d = 0; d < ND; ++d) acc += sIm[d] * Wwk[t * ND + d];
        sIp[t] = acc;
    }
    __syncthreads();

    if (t < ND) {
        float e = 0.f, a = 0.f;
#pragma unroll
        for (int r = 0; r < NR; ++r) {
            float ip = sIp[r];
            e += ip * Wwe[t * NR + r];
            a += ip * Wwa[t * NR + r];
        }
        sOmE[t] = 1.0f - 1.0f / (1.0f + __expf(-e));
        sAdd[t] = a;
    }
    __syncthreads();

    // layer norm each of the 16 memory rows; one wave per row
    const int wave = t >> 6, lane = t & 63;
    for (int m = wave; m < NM; m += 4) {
        const float* mrow = memory + ((size_t)b * NM + m) * ND;
        float v0 = mrow[lane] * sOmE[lane] + sAdd[lane];
        float v1 = mrow[lane + 64] * sOmE[lane + 64] + sAdd[lane + 64];
        float v2 = 0.f;
        const bool has2 = lane < 32;
        if (has2) v2 = mrow[lane + 128] * sOmE[lane + 128] + sAdd[lane + 128];
        float s  = v0 + v1 + v2;
        float sq = v0 * v0 + v1 * v1 + v2 * v2;
#pragma unroll
        for (int off = 32; off; off >>= 1) {
            s  += __shfl_xor(s, off);
            sq += __shfl_xor(sq, off);
        }
        float mu   = s * (1.0f / ND);
        float var  = sq * (1.0f / ND) - mu * mu;
        float rstd = rsqrtf(var + 1e-5f);
        float* orow = new_mem + ((size_t)b * NM + m) * ND;
        orow[lane]      = (v0 - mu) * rstd;
        orow[lane + 64] = (v1 - mu) * rstd;
        if (has2) orow[lane + 128] = (v2 - mu) * rstd;
    }
}

extern "C" void kernel_launch(void* const* d_in, const int* in_sizes, int n_in,
                              void* d_out, int out_size, void* d_ws, size_t ws_size,
                              hipStream_t stream) {
    const float* query  = (const float*)d_in[0];
    const float* iface  = (const float*)d_in[1];
    const float* memory = (const float*)d_in[2];
    const float* Wrk    = (const float*)d_in[3];
    const float* Wrv    = (const float*)d_in[4];
    const float* Wwk    = (const float*)d_in[5];
    const float* Wwe    = (const float*)d_in[6];
    const float* Wwa    = (const float*)d_in[7];

    float* read_out = (float*)d_out;                        // [32][4096][160]
    float* new_mem  = (float*)d_out + (size_t)NB * NS * ND; // [32][16][160]
    float* ipart    = (float*)d_ws;                         // NB*NCB*ND f32
    float* kvbuf    = (float*)d_ws + (size_t)NB * NCB * ND; // NB*2*NM*ND f32

    ulm_fold_kv<<<NB, 256, 0, stream>>>(memory, Wrk, Wrv, kvbuf);
    dim3 grid1(NCB, NB);
    ulm_read_kernel<<<grid1, 256, 0, stream>>>(query, iface, kvbuf,
                                               read_out, ipart);
    ulm_write_kernel<<<NB, 256, 0, stream>>>(memory, Wwk, Wwe, Wwa, ipart, new_mem);
}